// Round 11
// baseline (266.787 us; speedup 1.0000x reference)
//
#include <hip/hip_runtime.h>
#include <hip/hip_bf16.h>
#include <hip/hip_fp8.h>

#define TT 36
#define FF 18
#define HH 128
#define BB 16
#define BLOCK 512
#define SIGP 36   // es/el row length (floats); 144 B rows, b128-aligned

typedef __attribute__((ext_vector_type(4))) float f32x4;
typedef __attribute__((ext_vector_type(2))) float f32x2;

#define L2E  1.4426950408889634f
#define L2E2 2.8853900817779268f

#if __has_builtin(__builtin_amdgcn_rcpf)
static __device__ __forceinline__ float frcp(float x) { return __builtin_amdgcn_rcpf(x); }
#else
static __device__ __forceinline__ float frcp(float x) { return 1.f / x; }
#endif
#if __has_builtin(__builtin_amdgcn_exp2f)
static __device__ __forceinline__ float fexp2(float x) { return __builtin_amdgcn_exp2f(x); }
#else
static __device__ __forceinline__ float fexp2(float x) { return __expf(x * 0.69314718056f); }
#endif

// float -> fp8 e4m3 (OCP), RNE
#if __has_builtin(__builtin_amdgcn_cvt_pk_fp8_f32)
static __device__ __forceinline__ unsigned char f2fp8(float f) {
    int v = __builtin_amdgcn_cvt_pk_fp8_f32(f, 0.f, 0, false);
    return (unsigned char)(v & 0xff);
}
#else
static __device__ __forceinline__ unsigned char f2fp8(float f) {
    __hip_fp8_e4m3 q(f);
    return *(unsigned char*)&q;
}
#endif

static __device__ __forceinline__ f32x4 mfma_f8(long a, long b, f32x4 c) {
    return __builtin_amdgcn_mfma_f32_16x16x32_fp8_fp8(a, b, c, 0, 0, 0);
}

// CDNA packed dual-FP32 FMA (VOP3P). Compiler won't auto-pack; do it by hand.
static __device__ __forceinline__ f32x2 pk_fma(f32x2 a, f32x2 b, f32x2 c) {
    f32x2 d;
    asm("v_pk_fma_f32 %0, %1, %2, %3" : "=v"(d) : "v"(a), "v"(b), "v"(c));
    return d;
}

union F8x8 { unsigned char b[8]; long l; };
union V4 { f32x4 v4; f32x2 v2[2]; float f[4]; };

// XOR chunk swizzle for 8-byte fp8 chunks: chunk (c, bb) at slot bb^c of chunk-row c.
static __device__ __forceinline__ unsigned hxoff(int c, int bb) {
    return (unsigned)((c * BB + (bb ^ c)) << 3);
}

__global__ __launch_bounds__(BLOCK, 4) void enc_att_gru(
    const float* __restrict__ seqs, const float* __restrict__ mask,
    const float* __restrict__ Wh,   const float* __restrict__ bh,
    const float* __restrict__ Ws,   const float* __restrict__ bs,
    const float* __restrict__ Wo,   const float* __restrict__ bo,
    const float* __restrict__ W_ih, const float* __restrict__ W_hh,
    const float* __restrict__ b_ih, const float* __restrict__ b_hh,
    float* __restrict__ out)
{
    __shared__ __align__(16) float es_lds[BB * FF * SIGP];   // Es = exp2(L2E2*sig), 41472 B
    __shared__ float Ws2_lds[TT * TT];                       // [tp][t], pre-scaled L2E2
    __shared__ float bs2_lds[TT];
    __shared__ __align__(16) float wo2_lds[TT];              // -2*wo
    __shared__ __align__(16) float el_lds[BB][SIGP];         // El = exp2(L2E2*lin_h)
    __shared__ __align__(16) unsigned char h_lds[16 * BB * 8]; // fp8 h, swizzled chunks
    __shared__ __align__(16) unsigned char x_lds[4 * BB * 8];  // fp8 x, swizzled chunks
    __shared__ __align__(16) float mask_t[TT][BB];           // transposed mask
    __shared__ __align__(16) long whf_lds[4 * 3 * 64];       // lin_h fp8 B-frags, 6 KB

    const int tid  = threadIdx.x;
    const int wave = tid >> 6;
    const int lane = tid & 63;
    const int l15  = lane & 15;
    const int l4   = lane >> 4;
    const int bbase = blockIdx.x * BB;
    const int bb2 = tid >> 5;      // phase-B batch row (0..15)
    const int f2  = tid & 31;      // phase-B feature (valid < 18)
    const int fsafe = (f2 < FF) ? f2 : (FF - 1);

    // ---- stage small tensors ----
    for (int idx = tid; idx < TT * TT; idx += BLOCK) {
        int t = idx / TT, tp = idx - t * TT;
        Ws2_lds[tp * TT + t] = L2E2 * Ws[idx];      // transposed + scaled
    }
    if (tid < TT) { bs2_lds[tid] = L2E2 * bs[tid]; wo2_lds[tid] = -2.f * Wo[tid]; }
    for (int idx = tid; idx < BB * TT; idx += BLOCK) {
        int bb = idx / TT, t = idx - bb * TT;
        mask_t[t][bb] = mask[(size_t)(bbase + bb) * TT + t];
    }
    for (int idx = tid; idx < 16 * BB * 2; idx += BLOCK) ((int*)h_lds)[idx] = 0;
    for (int idx = tid; idx < 4 * BB * 2; idx += BLOCK) ((int*)x_lds)[idx] = 0;
    // lin_h fp8 B-frag table: (kt, w, l) -> Wh[w*16 + (l&15)][kt*32 + ((l>>4)&3)*8 + jj]
    for (int e = tid; e < 4 * 3 * 64; e += BLOCK) {
        int kt = e / 192;
        int w  = (e / 64) % 3;
        int l  = e & 63;
        int tcolw = w * 16 + (l & 15);
        int kb = kt * 32 + ((l >> 4) & 3) * 8;
        F8x8 u;
#pragma unroll
        for (int jj = 0; jj < 8; ++jj)
            u.b[jj] = (tcolw < TT) ? f2fp8(Wh[(size_t)tcolw * HH + kb + jj]) : (unsigned char)0;
        whf_lds[e] = u.l;
    }
    __syncthreads();

    // ---- precompute Es[bb][f][t] = exp2( L2E2*(bs[t] + sum_tp seq[bb][tp][f]*Ws[t][tp]) ) ----
    if (f2 < FF) {
        const size_t sb = (size_t)(bbase + bb2) * (TT * FF) + f2;
        float* srow = &es_lds[(bb2 * FF + f2) * SIGP];
        for (int c = 0; c < 3; ++c) {              // t in chunks of 12
            float acc[12];
#pragma unroll
            for (int j = 0; j < 12; ++j) acc[j] = bs2_lds[c * 12 + j];
            for (int tp = 0; tp < TT; ++tp) {
                float s = seqs[sb + (size_t)tp * FF];
#pragma unroll
                for (int j = 0; j < 12; ++j)
                    acc[j] = fmaf(s, Ws2_lds[tp * TT + c * 12 + j], acc[j]);
            }
#pragma unroll
            for (int j = 0; j < 12; ++j) srow[c * 12 + j] = fexp2(acc[j]);
        }
    }

    // ---- persistent fp8 weight fragments (self-consistent k-map: k = kt*32 + l4*8 + j) ----
    long whh[3][4];
    for (int g = 0; g < 3; ++g)
        for (int kt = 0; kt < 4; ++kt) {
            const int o = g * HH + 16 * wave + l15;
            F8x8 u;
#pragma unroll
            for (int jj = 0; jj < 8; ++jj) {
                int k = kt * 32 + l4 * 8 + jj;
                u.b[jj] = f2fp8(W_hh[(size_t)o * HH + k]);
            }
            whh[g][kt] = u.l;
        }
    long wih[3];
    for (int g = 0; g < 3; ++g) {
        const int o = g * HH + 16 * wave + l15;
        F8x8 u;
#pragma unroll
        for (int jj = 0; jj < 8; ++jj) {
            int f = l4 * 8 + jj;
            u.b[jj] = (f < FF) ? f2fp8(W_ih[(size_t)o * FF + f]) : (unsigned char)0;
        }
        wih[g] = u.l;
    }
    const int tcol = 16 * wave + l15;
    const int junit = 16 * wave + l15;
    // pre-scaled packed gate constants
    const float brz_r = b_ih[junit] + b_hh[junit];
    const float brz_z = b_ih[HH + junit] + b_hh[HH + junit];
    const f32x2 one2   = {1.f, 1.f};
    const f32x2 cnL2E  = {-L2E, -L2E};
    const f32x2 cbrz_r = {-L2E * brz_r, -L2E * brz_r};
    const f32x2 cbrz_z = {-L2E * brz_z, -L2E * brz_z};
    const f32x2 cbn_i  = {b_ih[2 * HH + junit], b_ih[2 * HH + junit]};
    const f32x2 cbn_h  = {b_hh[2 * HH + junit], b_hh[2 * HH + junit]};
    const float bh_reg = (wave < 3 && tcol < TT) ? bh[tcol] : 0.f;
    const f32x2 cL2E2  = {L2E2, L2E2};
    const f32x2 cbh2   = {bh_reg * L2E2, bh_reg * L2E2};
    float c0 = bo[0];
    for (int tp = 0; tp < TT; ++tp) c0 += Wo[tp];   // e = c0 + sum wo2[t]*rcp(1+Es*El)

    float seq_cur = seqs[(size_t)(bbase + bb2) * (TT * FF) + fsafe];

    float h_prev[4]  = {0.f, 0.f, 0.f, 0.f};
    float out_acc[4] = {0.f, 0.f, 0.f, 0.f};

    __syncthreads();

    for (int t = 0; t < TT; ++t) {
        // ---- Phase A: h A-frags + lin_h (fp8 MFMA) -> El + gh MFMAs ----
        long ha[4];
#pragma unroll
        for (int kt = 0; kt < 4; ++kt)
            ha[kt] = *(const long*)(h_lds + hxoff(kt * 4 + l4, l15));
        if (wave < 3) {
            f32x4 a = {0.f, 0.f, 0.f, 0.f};
#pragma unroll
            for (int kt = 0; kt < 4; ++kt)
                a = mfma_f8(ha[kt], whf_lds[kt * 192 + wave * 64 + lane], a);
            if (tcol < TT) {
                V4 ua; ua.v4 = a;
                f32x2 g0 = pk_fma(ua.v2[0], cL2E2, cbh2);
                f32x2 g1 = pk_fma(ua.v2[1], cL2E2, cbh2);
                el_lds[l4 * 4 + 0][tcol] = fexp2(g0[0]);
                el_lds[l4 * 4 + 1][tcol] = fexp2(g0[1]);
                el_lds[l4 * 4 + 2][tcol] = fexp2(g1[0]);
                el_lds[l4 * 4 + 3][tcol] = fexp2(g1[1]);
            }
        }
        f32x4 acc_r = {0.f,0.f,0.f,0.f}, acc_z = {0.f,0.f,0.f,0.f}, acc_n = {0.f,0.f,0.f,0.f};
#pragma unroll
        for (int kt = 0; kt < 4; ++kt) {
            acc_r = mfma_f8(ha[kt], whh[0][kt], acc_r);
            acc_z = mfma_f8(ha[kt], whh[1][kt], acc_z);
            acc_n = mfma_f8(ha[kt], whh[2][kt], acc_n);
        }
        __syncthreads();   // el visible

        // ---- Phase B: e-scores (packed dual-FP32) + no-max softmax + x ----
        {
            const float* srow = &es_lds[(bb2 * FF + fsafe) * SIGP];
            const float* lrow = &el_lds[bb2][0];
            f32x2 acc0 = {c0, 0.f}, acc1 = {0.f, 0.f};
#pragma unroll
            for (int g = 0; g < 9; ++g) {
                V4 sv, lv, wv;
                sv.v4 = *(const f32x4*)(srow + g * 4);
                lv.v4 = *(const f32x4*)(lrow + g * 4);
                wv.v4 = *(const f32x4*)(&wo2_lds[g * 4]);
                f32x2 t0 = pk_fma(sv.v2[0], lv.v2[0], one2);
                f32x2 t1 = pk_fma(sv.v2[1], lv.v2[1], one2);
                f32x2 r0 = {frcp(t0[0]), frcp(t0[1])};
                f32x2 r1 = {frcp(t1[0]), frcp(t1[1])};
                acc0 = pk_fma(wv.v2[0], r0, acc0);
                acc1 = pk_fma(wv.v2[1], r1, acc1);
            }
            float eacc = (acc0[0] + acc1[0]) + (acc0[1] + acc1[1]);
            // |e| <= |bo| + sum|wo| ~ 1.5 -> exp2 can't overflow; skip max pass
            float p = (f2 < FF) ? fexp2(L2E * eacc) : 0.f;
            float s = p;
#pragma unroll
            for (int d = 1; d <= 16; d <<= 1) s += __shfl_xor(s, d);
            if (f2 < FF) {
                x_lds[hxoff(f2 >> 3, bb2) + (f2 & 7)] = f2fp8(p * frcp(s) * seq_cur);
                if (t + 1 < TT)
                    seq_cur = seqs[(size_t)(bbase + bb2) * (TT * FF) + (size_t)(t + 1) * FF + f2];
            }
        }
        __syncthreads();   // x visible

        // ---- Phase C: gi MFMA (fp8) + GRU elementwise (packed args) + h store ----
        long xa = *(const long*)(x_lds + hxoff(l4, l15));
        acc_r = mfma_f8(xa, wih[0], acc_r);
        acc_z = mfma_f8(xa, wih[1], acc_z);
        f32x4 zero4 = {0.f, 0.f, 0.f, 0.f};
        f32x4 acc_gi = mfma_f8(xa, wih[2], zero4);
        {
            V4 uar, uaz, uan, ugi, mv;
            uar.v4 = acc_r; uaz.v4 = acc_z; uan.v4 = acc_n; ugi.v4 = acc_gi;
            mv.v4 = *(const f32x4*)(&mask_t[t][l4 * 4]);
            f32x2 argr[2] = { pk_fma(uar.v2[0], cnL2E, cbrz_r), pk_fma(uar.v2[1], cnL2E, cbrz_r) };
            f32x2 argz[2] = { pk_fma(uaz.v2[0], cnL2E, cbrz_z), pk_fma(uaz.v2[1], cnL2E, cbrz_z) };
            f32x2 ghn[2]  = { pk_fma(uan.v2[0], one2, cbn_h), pk_fma(uan.v2[1], one2, cbn_h) };
            f32x2 gia[2]  = { pk_fma(ugi.v2[0], one2, cbn_i), pk_fma(ugi.v2[1], one2, cbn_i) };
#pragma unroll
            for (int r = 0; r < 4; ++r) {
                int bb = l4 * 4 + r;
                float rg = frcp(1.f + fexp2(argr[r >> 1][r & 1]));
                float zg = frcp(1.f + fexp2(argz[r >> 1][r & 1]));
                float gin = fmaf(rg, ghn[r >> 1][r & 1], gia[r >> 1][r & 1]);
                float ng = fmaf(-2.f, frcp(1.f + fexp2(L2E2 * gin)), 1.f);
                float hn = fmaf(zg, h_prev[r] - ng, ng);
                h_prev[r] = hn;
                out_acc[r] = fmaf(hn, mv.f[r], out_acc[r]);
                h_lds[hxoff(junit >> 3, bb) + (junit & 7)] = f2fp8(hn);
            }
        }
        __syncthreads();   // h ready for next step
    }

#pragma unroll
    for (int r = 0; r < 4; ++r) {
        int bb = l4 * 4 + r;
        out[(size_t)(bbase + bb) * HH + junit] = out_acc[r];
    }
}

extern "C" void kernel_launch(void* const* d_in, const int* in_sizes, int n_in,
                              void* d_out, int out_size, void* d_ws, size_t ws_size,
                              hipStream_t stream) {
    const float* seqs = (const float*)d_in[0];
    const float* mask = (const float*)d_in[1];
    const float* Wh   = (const float*)d_in[2];
    const float* bh   = (const float*)d_in[3];
    const float* Ws   = (const float*)d_in[4];
    const float* bs   = (const float*)d_in[5];
    const float* Wo   = (const float*)d_in[6];
    const float* bo   = (const float*)d_in[7];
    const float* W_ih = (const float*)d_in[8];
    const float* W_hh = (const float*)d_in[9];
    const float* b_ih = (const float*)d_in[10];
    const float* b_hh = (const float*)d_in[11];
    float* out = (float*)d_out;

    const int Btot = in_sizes[0] / (TT * FF);   // 16384
    const int grid = Btot / BB;                 // 1024
    enc_att_gru<<<grid, BLOCK, 0, stream>>>(seqs, mask, Wh, bh, Ws, bs, Wo, bo,
                                            W_ih, W_hh, b_ih, b_hh, out);
}